// Round 1
// baseline (519.300 us; speedup 1.0000x reference)
//
#include <hip/hip_runtime.h>
#include <cstdint>

// ---------------------------------------------------------------------------
// DeepSpeedSelfAttention fused: LN -> QKV GEMM -> flash attention -> out proj
// B=4 S=2048 H=1024 HEADS=16 DHEAD=64. All GEMM-shaped compute in bf16 MFMA
// (16x16x32), fp32 accumulate. Outputs (flat, in order):
//   [0] output  = ctx @ ow^T            (8388608 f32)
//   [1] key     = qkv[:,1024:2048]      (8388608 f32)
//   [2] value   = qkv[:,2048:3072]      (8388608 f32)
//   [3] context                          (8388608 f32)
// ---------------------------------------------------------------------------

typedef __attribute__((ext_vector_type(8))) short short8;
typedef __attribute__((ext_vector_type(4))) short short4v;
typedef __attribute__((ext_vector_type(4))) float floatx4;

#define BSH 8388608            // B*S*H
#define PART_STRIDE 8388608    // q/k/v part stride in ws head-layout (elems)

static __device__ __forceinline__ short f2bf(float f) {
  union { float f; uint32_t u; } v; v.f = f;
  uint32_t r = v.u + 0x7fffu + ((v.u >> 16) & 1u);  // round-to-nearest-even
  return (short)(r >> 16);
}

// ---- fp32 -> bf16 weight conversion (wqkv 3072x1024, ow 1024x1024) --------
__global__ __launch_bounds__(256) void k_convert(const float4* __restrict__ wqkv,
                                                 const float4* __restrict__ ow,
                                                 short4v* __restrict__ dq,
                                                 short4v* __restrict__ dow) {
  const int n1 = (3072 * 1024) / 4, n2 = (1024 * 1024) / 4;
  for (int i = blockIdx.x * 256 + threadIdx.x; i < n1 + n2; i += gridDim.x * 256) {
    float4 v = (i < n1) ? wqkv[i] : ow[i - n1];
    short4v s;
    s[0] = f2bf(v.x); s[1] = f2bf(v.y); s[2] = f2bf(v.z); s[3] = f2bf(v.w);
    if (i < n1) dq[i] = s; else dow[i - n1] = s;
  }
}

// ---- LayerNorm: one block per row of 1024, bf16 out ------------------------
__global__ __launch_bounds__(256) void k_ln(const float* __restrict__ x,
                                            const float* __restrict__ w,
                                            const float* __restrict__ bb,
                                            short* __restrict__ out) {
  const int row = blockIdx.x, t = threadIdx.x;
  float4 v = ((const float4*)(x + row * 1024))[t];
  float s = v.x + v.y + v.z + v.w;
  float sq = v.x * v.x + v.y * v.y + v.z * v.z + v.w * v.w;
#pragma unroll
  for (int off = 32; off; off >>= 1) { s += __shfl_down(s, off); sq += __shfl_down(sq, off); }
  __shared__ float ls[4], lq[4];
  if ((t & 63) == 0) { ls[t >> 6] = s; lq[t >> 6] = sq; }
  __syncthreads();
  s = ls[0] + ls[1] + ls[2] + ls[3];
  sq = lq[0] + lq[1] + lq[2] + lq[3];
  float mu = s * (1.0f / 1024.0f);
  float var = sq * (1.0f / 1024.0f) - mu * mu;
  float rs = rsqrtf(fmaxf(var, 0.0f) + 1e-12f);
  float4 wv = ((const float4*)w)[t];
  float4 bv = ((const float4*)bb)[t];
  short4v o;
  o[0] = f2bf((v.x - mu) * rs * wv.x + bv.x);
  o[1] = f2bf((v.y - mu) * rs * wv.y + bv.y);
  o[2] = f2bf((v.z - mu) * rs * wv.z + bv.z);
  o[3] = f2bf((v.w - mu) * rs * wv.w + bv.w);
  ((short4v*)out)[row * 256 + t] = o;
}

// ---- bf16 GEMM C[M,N] = A[M,K] @ Bm[N,K]^T, 128x128x32 tiles ---------------
// MODE 0: QKV epilogue (+bias; key/value fp32 -> d_out; q/k/v bf16 head layout)
// MODE 1: plain fp32 store to out[gr*N+gc]
// LDS chunk swizzle: chunk c of row stored at c ^ ((row>>1)&3) -> ds_read_b128
// frag reads land 2-way bank aliased (free on CDNA4, m136).
template <int MODE>
__global__ __launch_bounds__(256) void k_gemm(const short* __restrict__ A,
                                              const short* __restrict__ Bm,
                                              const float* __restrict__ bias,
                                              float* __restrict__ out,
                                              short* __restrict__ qkvh,
                                              int K, int N) {
  __shared__ short As[128 * 32], Bs[128 * 32];
  const int tid = threadIdx.x, lane = tid & 63, w = tid >> 6;
  const int quad = lane >> 4, l15 = lane & 15;
  const int wr = w >> 1, wc = w & 1;
  const int m0 = blockIdx.y * 128, n0 = blockIdx.x * 128;
  floatx4 acc[4][4] = {};
  for (int k0 = 0; k0 < K; k0 += 32) {
#pragma unroll
    for (int r = 0; r < 2; r++) {
      int idx = r * 256 + tid;
      int row = idx >> 2, c = idx & 3;
      int sw = c ^ ((row >> 1) & 3);
      *(short8*)&As[row * 32 + sw * 8] = *(const short8*)&A[(m0 + row) * K + k0 + c * 8];
      *(short8*)&Bs[row * 32 + sw * 8] = *(const short8*)&Bm[(n0 + row) * K + k0 + c * 8];
    }
    __syncthreads();
    short8 af[4], bf[4];
#pragma unroll
    for (int i = 0; i < 4; i++) {
      int ar = wr * 64 + i * 16 + l15;
      af[i] = *(const short8*)&As[ar * 32 + ((quad ^ ((ar >> 1) & 3)) * 8)];
      int br = wc * 64 + i * 16 + l15;
      bf[i] = *(const short8*)&Bs[br * 32 + ((quad ^ ((br >> 1) & 3)) * 8)];
    }
#pragma unroll
    for (int i = 0; i < 4; i++)
#pragma unroll
      for (int j = 0; j < 4; j++)
        acc[i][j] = __builtin_amdgcn_mfma_f32_16x16x32_bf16(af[i], bf[j], acc[i][j], 0, 0, 0);
    __syncthreads();
  }
  // epilogue. C/D layout: col = lane&15, row = quad*4 + reg (m89-verified)
  const int grB = m0 + wr * 64, gcB = n0 + wc * 64;
#pragma unroll
  for (int i = 0; i < 4; i++) {
#pragma unroll
    for (int j = 0; j < 4; j++) {
      int gc = gcB + j * 16 + l15;
      if (MODE == 0) {
        float bv = bias[gc];
        int part = gc >> 10, within = gc & 1023;
        int head = within >> 6, dd = within & 63;
#pragma unroll
        for (int reg = 0; reg < 4; reg++) {
          int gr = grB + i * 16 + quad * 4 + reg;
          float val = acc[i][j][reg] + bv;
          int b_ = gr >> 11, s_ = gr & 2047;
          qkvh[part * PART_STRIDE + ((b_ * 16 + head) * 2048 + s_) * 64 + dd] = f2bf(val);
          if (part == 1) out[BSH + gr * 1024 + within] = val;
          else if (part == 2) out[2 * BSH + gr * 1024 + within] = val;
        }
      } else {
#pragma unroll
        for (int reg = 0; reg < 4; reg++) {
          int gr = grB + i * 16 + quad * 4 + reg;
          out[gr * N + gc] = acc[i][j][reg];
        }
      }
    }
  }
}

// ---- flash attention: block = (qt, h, b), 128 q-rows, BK=64 ----------------
// Wave owns 32 q-rows. Q A-frags pinned in regs. K LDS layout [s][d] serves
// directly as the K^T B-operand; V staged transposed [d][s] for PV B-operand;
// P goes C-layout -> LDS(bf16) -> A-layout (m120 transform). 8-chunk XOR
// swizzle (^row&7) keeps all ds_read_b128 at 2-way.
__global__ __launch_bounds__(256) void k_attn(const short* __restrict__ qkvh,
                                              const float* __restrict__ mask,
                                              float* __restrict__ ctx_out,
                                              short* __restrict__ ctx_bf) {
  const int qt = blockIdx.x, h = blockIdx.y, b = blockIdx.z;
  const int tid = threadIdx.x, lane = tid & 63, w = tid >> 6;
  const int quad = lane >> 4, l15 = lane & 15;
  __shared__ short Ks[64 * 64];
  __shared__ short Vt[64 * 64];
  __shared__ short Pl[128 * 64];
  const short* qg = qkvh + ((b * 16 + h) * 2048) * 64;
  const short* kg = qg + PART_STRIDE;
  const short* vg = kg + PART_STRIDE;
  const float* mb = mask + b * 2048;

  short8 qf[2][2];
  const int qr0 = qt * 128 + w * 32;
#pragma unroll
  for (int mt = 0; mt < 2; mt++)
#pragma unroll
    for (int ks = 0; ks < 2; ks++)
      qf[mt][ks] = *(const short8*)&qg[(qr0 + mt * 16 + l15) * 64 + ks * 32 + quad * 8];

  floatx4 accO[2][4] = {};
  float mrun[2][4], lrun[2][4];
#pragma unroll
  for (int mt = 0; mt < 2; mt++)
#pragma unroll
    for (int r = 0; r < 4; r++) { mrun[mt][r] = -1e30f; lrun[mt][r] = 0.0f; }

  const int vc = tid >> 5, vp = tid & 31;  // V transpose: d-chunk, s-pair

  for (int kt = 0; kt < 32; kt++) {
    const int s0 = kt * 64;
    // stage K [64 s][64 d], swizzled
#pragma unroll
    for (int r = 0; r < 2; r++) {
      int idx = r * 256 + tid;
      int row = idx >> 3, c = idx & 7;
      *(short8*)&Ks[row * 64 + ((c ^ (row & 7)) * 8)] =
          *(const short8*)&kg[(s0 + row) * 64 + c * 8];
    }
    // stage V transposed -> Vt[d][s] (packed pair writes), swizzled
    {
      short8 r0 = *(const short8*)&vg[(s0 + 2 * vp) * 64 + vc * 8];
      short8 r1 = *(const short8*)&vg[(s0 + 2 * vp + 1) * 64 + vc * 8];
#pragma unroll
      for (int j = 0; j < 8; j++) {
        int d = vc * 8 + j;
        int swc = (vp >> 2) ^ (d & 7);
        ((int*)Vt)[d * 32 + swc * 4 + (vp & 3)] =
            (int)(uint16_t)r0[j] | ((int)(uint16_t)r1[j] << 16);
      }
    }
    __syncthreads();

    // S = Q K^T  (16 MFMA)
    floatx4 sc[2][4] = {};
#pragma unroll
    for (int nt = 0; nt < 4; nt++) {
      int krow = nt * 16 + l15;
#pragma unroll
      for (int ks = 0; ks < 2; ks++) {
        short8 kf = *(const short8*)&Ks[krow * 64 + (((ks * 4 + quad) ^ (krow & 7)) * 8)];
#pragma unroll
        for (int mt = 0; mt < 2; mt++)
          sc[mt][nt] = __builtin_amdgcn_mfma_f32_16x16x32_bf16(qf[mt][ks], kf, sc[mt][nt], 0, 0, 0);
      }
    }
    float mv[4];
#pragma unroll
    for (int nt = 0; nt < 4; nt++) mv[nt] = mb[s0 + nt * 16 + l15];

    // online softmax per 32-row band (rows live at quad*4+reg; cols at l15)
#pragma unroll
    for (int mt = 0; mt < 2; mt++) {
      float rm[4];
#pragma unroll
      for (int reg = 0; reg < 4; reg++) {
        float x = -1e30f;
#pragma unroll
        for (int nt = 0; nt < 4; nt++) {
          float sv = sc[mt][nt][reg] * 0.125f + mv[nt];
          sc[mt][nt][reg] = sv;
          x = fmaxf(x, sv);
        }
        rm[reg] = x;
      }
#pragma unroll
      for (int off = 1; off < 16; off <<= 1)
#pragma unroll
        for (int reg = 0; reg < 4; reg++)
          rm[reg] = fmaxf(rm[reg], __shfl_xor(rm[reg], off));
      float alpha[4], rsum[4];
#pragma unroll
      for (int reg = 0; reg < 4; reg++) {
        float mnew = fmaxf(mrun[mt][reg], rm[reg]);
        alpha[reg] = __expf(mrun[mt][reg] - mnew);
        mrun[mt][reg] = mnew;
        float rs_ = 0.0f;
#pragma unroll
        for (int nt = 0; nt < 4; nt++) {
          float p = __expf(sc[mt][nt][reg] - mnew);
          sc[mt][nt][reg] = p;
          rs_ += p;
        }
        rsum[reg] = rs_;
      }
#pragma unroll
      for (int off = 1; off < 16; off <<= 1)
#pragma unroll
        for (int reg = 0; reg < 4; reg++)
          rsum[reg] += __shfl_xor(rsum[reg], off);
#pragma unroll
      for (int reg = 0; reg < 4; reg++) {
        lrun[mt][reg] = lrun[mt][reg] * alpha[reg] + rsum[reg];
#pragma unroll
        for (int nt2 = 0; nt2 < 4; nt2++) accO[mt][nt2][reg] *= alpha[reg];
      }
      // P: C-layout -> LDS bf16 (wave-private band; DS ops in-order per wave,
      // compiler inserts lgkmcnt before the dependent ds_read)
#pragma unroll
      for (int nt = 0; nt < 4; nt++) {
        int colc = nt * 2 + (l15 >> 3);
#pragma unroll
        for (int reg = 0; reg < 4; reg++) {
          int prow = w * 32 + mt * 16 + quad * 4 + reg;
          Pl[prow * 64 + ((colc ^ (prow & 7)) * 8) + (l15 & 7)] = f2bf(sc[mt][nt][reg]);
        }
      }
    }

    // O += P V  (16 MFMA)
#pragma unroll
    for (int ks2 = 0; ks2 < 2; ks2++) {
      short8 vf[4];
#pragma unroll
      for (int nt2 = 0; nt2 < 4; nt2++) {
        int vrow = nt2 * 16 + l15;
        vf[nt2] = *(const short8*)&Vt[vrow * 64 + (((ks2 * 4 + quad) ^ (vrow & 7)) * 8)];
      }
#pragma unroll
      for (int mt = 0; mt < 2; mt++) {
        int prow = w * 32 + mt * 16 + l15;
        short8 pf = *(const short8*)&Pl[prow * 64 + (((ks2 * 4 + quad) ^ (prow & 7)) * 8)];
#pragma unroll
        for (int nt2 = 0; nt2 < 4; nt2++)
          accO[mt][nt2] = __builtin_amdgcn_mfma_f32_16x16x32_bf16(pf, vf[nt2], accO[mt][nt2], 0, 0, 0);
      }
    }
    __syncthreads();  // protect Ks/Vt/Pl before next stage
  }

  // epilogue: context fp32 to d_out slice 3, bf16 to ws for the out-proj GEMM
#pragma unroll
  for (int mt = 0; mt < 2; mt++)
#pragma unroll
    for (int nt2 = 0; nt2 < 4; nt2++)
#pragma unroll
      for (int reg = 0; reg < 4; reg++) {
        int qrow = qt * 128 + w * 32 + mt * 16 + quad * 4 + reg;
        int col = h * 64 + nt2 * 16 + l15;
        int gi = (b * 2048 + qrow) * 1024 + col;
        float val = accO[mt][nt2][reg] / lrun[mt][reg];
        ctx_out[gi] = val;
        ctx_bf[gi] = f2bf(val);
      }
}

// ---------------------------------------------------------------------------
extern "C" void kernel_launch(void* const* d_in, const int* in_sizes, int n_in,
                              void* d_out, int out_size, void* d_ws, size_t ws_size,
                              hipStream_t stream) {
  const float* x    = (const float*)d_in[0];
  const float* mask = (const float*)d_in[1];
  const float* nw   = (const float*)d_in[2];
  const float* nb   = (const float*)d_in[3];
  const float* wqkv = (const float*)d_in[4];
  const float* bqkv = (const float*)d_in[5];
  const float* ow   = (const float*)d_in[6];
  float* out = (float*)d_out;
  char* ws = (char*)d_ws;

  // ws layout (bytes): [0,16M) ln_bf16 (later aliased as ctx_bf16);
  // [16M, 22.3M) wqkv bf16; [22.3M, 24M) ow bf16; [24M, 72M) qkv head-layout
  short* lnb   = (short*)ws;                   // 8192*1024 bf16 (16.78 MB)
  short* wqkvb = (short*)(ws + 16777216);      // 3072*1024 bf16
  short* owb   = (short*)(ws + 23068672);      // 1024*1024 bf16
  short* qkvh  = (short*)(ws + 25165824);      // 3*8192*1024 bf16 (50.3 MB)

  k_convert<<<512, 256, 0, stream>>>((const float4*)wqkv, (const float4*)ow,
                                     (short4v*)wqkvb, (short4v*)owb);
  k_ln<<<8192, 256, 0, stream>>>(x, nw, nb, lnb);
  k_gemm<0><<<dim3(24, 64), 256, 0, stream>>>(lnb, wqkvb, bqkv, out, qkvh, 1024, 3072);
  k_attn<<<dim3(16, 16, 4), 256, 0, stream>>>(qkvh, mask, out + 3 * (size_t)BSH, lnb);
  k_gemm<1><<<dim3(8, 64), 256, 0, stream>>>(lnb, owb, nullptr, out, nullptr, 1024, 1024);
}